// Round 7
// baseline (342.068 us; speedup 1.0000x reference)
//
#include <hip/hip_runtime.h>
#include <stdint.h>

// Hamming distance as an MX-FP4 MFMA GEMM, LDS-free / barrier-free:
// fragments stream directly global->VGPR (operands are 12 MB, L2/L3-resident;
// packed layout == fragment layout so loads are plain dwordx4).
// Token t -> 3 features (s1, s0, s1*s0), s=+-1, fp4 e2m1 (+1=0x2, -1=0xA),
// scales 1.0 (0x7F). dot = 4*matches - 512 => dist = 512 - ((dot+512)>>2).
//
// Packed layout: pk[R(32 row-groups of 256)][s(24 slices)][g(2)][r(256)][16B],
// slice s = K-chunk of 64 fp4 elems; lane l holds half g=l>>5, 32 elems = 16B.

#define NROWS 8192

typedef int   v4i  __attribute__((ext_vector_type(4)));
typedef int   v8i  __attribute__((ext_vector_type(8)));
typedef float v16f __attribute__((ext_vector_type(16)));

// ---------------- pack (unchanged from R6; proven) --------------------------
__global__ __launch_bounds__(512) void pack_kernel(
    const int* __restrict__ xq, const int* __restrict__ xp,
    uint8_t* __restrict__ qpk, uint8_t* __restrict__ ppk) {
  __shared__ uint8_t lt[64 * 384];      // [rl(64)][c(3)][chunk(8)^swz][16B]
  const int bid = blockIdx.x;           // 512 = 128 R64 * 2 dh * 2 op
  const int op  = bid & 1;
  const int dh  = (bid >> 1) & 1;
  const int R64 = bid >> 2;
  const int t   = threadIdx.x;
  const int* src = op ? xp : xq;
  uint8_t*   dst = op ? ppk : qpk;
  const int row0 = R64 * 64;
  const int d0   = dh * 256;

  #pragma unroll
  for (int i = 0; i < 8; ++i) {
    const int idx = i * 512 + t;
    const int rl = idx >> 6, q = idx & 63;
    const int4 a = ((const int4*)(src + (size_t)(row0 + rl) * 512 + d0))[q];
    const int tok[4] = {a.x, a.y, a.z, a.w};
    uint32_t n0 = 0, n1 = 0, n2 = 0;
    #pragma unroll
    for (int j = 0; j < 4; ++j) {
      const uint32_t b1 = (tok[j] >> 1) & 1, b0 = tok[j] & 1;
      n0 |= (0x2u | (b1 << 3)) << (4 * j);
      n1 |= (0x2u | (b0 << 3)) << (4 * j);
      n2 |= (0x2u | ((b1 ^ b0) << 3)) << (4 * j);
    }
    uint8_t* p = lt + rl * 384 + (((q >> 3) ^ (rl & 7)) << 4) + (q & 7) * 2;
    *(uint16_t*)(p)       = (uint16_t)n0;
    *(uint16_t*)(p + 128) = (uint16_t)n1;
    *(uint16_t*)(p + 256) = (uint16_t)n2;
  }
  __syncthreads();

  const size_t Rg = R64 >> 2;
  const int rb = (R64 & 3) * 64;
  #pragma unroll
  for (int i = 0; i < 3; ++i) {
    const int o = i * 512 + t;
    const int c = o >> 9, sg = (o >> 6) & 7, rl = o & 63;
    const int kt = c * 2 + dh;
    const uint4 v = *(const uint4*)(lt + rl * 384 + c * 128 + ((sg ^ (rl & 7)) << 4));
    *(uint4*)(dst + (((Rg * 6 + kt) * 8 + sg) * 256 + rb + rl) * 16) = v;
  }
}

// ---------------- main GEMM: no LDS, no barriers, 4-slice register ring -----
// Block = 4 waves (2x2), block tile 256(M) x 128(N); wave tile 128x64.
__global__ __launch_bounds__(256, 2) void hamming_mfma(
    const uint8_t* __restrict__ Apk, const uint8_t* __restrict__ Bpk,
    int* __restrict__ out) {
  const int t = threadIdx.x, l = t & 63, w = t >> 6;
  const int wr = w >> 1, wc = w & 1;

  // XCD swizzle (2048 % 8 == 0) + 8x8 (br,bc) patches: per-patch working set
  // = 8*256*768B (A) + 8*128*768B (B) = 2.25 MB -> fits a 4 MB XCD L2.
  const int bid = blockIdx.x;
  const int nid = (bid & 7) * 256 + (bid >> 3);
  const int q = nid & 63, p = nid >> 6;
  const int br = (p >> 3) * 8 + (q >> 3);          // 0..31
  const int bc = (p & 7) * 8 + (q & 7);            // 0..63

  const int g = l >> 5, ll = l & 31;
  const uint8_t* abase = Apk + (size_t)br * 196608 + g * 4096
                       + (size_t)(wr * 128 + ll) * 16;
  const uint8_t* bbase = Bpk + (size_t)(bc >> 1) * 196608 + g * 4096
                       + (size_t)((bc & 1) * 128 + wc * 64 + ll) * 16;

  v4i af[4][4], bf[4][2];                // 4-slice ring, static indices only
  v16f acc[4][2] = {};

  // prologue: slices 0..3 in flight (24 dwordx4 loads)
  #pragma unroll
  for (int i = 0; i < 4; ++i) {
    #pragma unroll
    for (int m = 0; m < 4; ++m)
      af[i][m] = *(const v4i*)(abase + i * 8192 + m * 512);
    #pragma unroll
    for (int n = 0; n < 2; ++n)
      bf[i][n] = *(const v4i*)(bbase + i * 8192 + n * 512);
  }

  for (int so = 0; so < 24; so += 4) {
    const int snext = (so + 4 == 24) ? 0 : so + 4;   // tail wrap (loads DCE'd)
    const uint8_t* pa = abase + snext * 8192;
    const uint8_t* pb = bbase + snext * 8192;
    #pragma unroll
    for (int i = 0; i < 4; ++i) {
      #pragma unroll
      for (int m = 0; m < 4; ++m)
        #pragma unroll
        for (int n = 0; n < 2; ++n) {
          const v8i av = (v8i){af[i][m][0], af[i][m][1], af[i][m][2], af[i][m][3],
                               0, 0, 0, 0};
          const v8i bv = (v8i){bf[i][n][0], bf[i][n][1], bf[i][n][2], bf[i][n][3],
                               0, 0, 0, 0};
          acc[m][n] = __builtin_amdgcn_mfma_scale_f32_32x32x64_f8f6f4(
              av, bv, acc[m][n], 4 /*fp4 A*/, 4 /*fp4 B*/,
              0, 0x7F7F7F7F, 0, 0x7F7F7F7F);
        }
      // refill ring slot i with slice snext+i (4 slices ahead of its use)
      #pragma unroll
      for (int m = 0; m < 4; ++m)
        af[i][m] = *(const v4i*)(pa + i * 8192 + m * 512);
      #pragma unroll
      for (int n = 0; n < 2; ++n)
        bf[i][n] = *(const v4i*)(pb + i * 8192 + n * 512);
    }
  }

  // epilogue: C/D (32x32): col = l&31, row = (reg&3) + 8*(reg>>2) + 4*(l>>5).
  // Nontemporal: output is write-once, keep it out of L2 (operands live there).
  const int rbase = br * 256 + wr * 128 + 4 * (l >> 5);
  const int cbase = bc * 128 + wc * 64 + (l & 31);
  #pragma unroll
  for (int m = 0; m < 4; ++m)
    #pragma unroll
    for (int n = 0; n < 2; ++n) {
      const int col = cbase + n * 32;
      #pragma unroll
      for (int reg = 0; reg < 16; ++reg) {
        const int orow = rbase + m * 32 + (reg & 3) + 8 * (reg >> 2);
        __builtin_nontemporal_store(
            512 - (((int)acc[m][n][reg] + 512) >> 2),
            &out[(size_t)orow * NROWS + col]);
      }
    }
}

extern "C" void kernel_launch(void* const* d_in, const int* in_sizes, int n_in,
                              void* d_out, int out_size, void* d_ws, size_t ws_size,
                              hipStream_t stream) {
  const int* xq = (const int*)d_in[0];
  const int* xp = (const int*)d_in[1];
  int* out = (int*)d_out;

  uint8_t* qpk = (uint8_t*)d_ws;                       // 6 MB
  uint8_t* ppk = qpk + (size_t)NROWS * 768;            // 6 MB

  pack_kernel<<<512, 512, 0, stream>>>(xq, xp, qpk, ppk);
  hamming_mfma<<<2048, 256, 0, stream>>>(qpk, ppk, out);
}

// Round 8
// 311.130 us; speedup vs baseline: 1.0994x; 1.0994x over previous
//
#include <hip/hip_runtime.h>
#include <stdint.h>

// Hamming distance as an MX-FP4 MFMA GEMM.
// Token t -> 3 features (s1, s0, s1*s0), s=+-1, fp4 e2m1 (+1=0x2, -1=0xA),
// scales 1.0 (0x7F). dot = 4*matches - 512 => dist = 512 - ((dot+512)>>2).
//
// Packed layout (validated R6): pk[R(32 groups of 256 rows)][s_glob(24)][g(2)][r(256)][16B]
//   = group*196608 + s_glob*8192 + g*4096 + r*16, s_glob = K-chunk of 64 fp4.
//
// R8 GEMM: 128x128 tile, 4 waves (2x2, wave tile 64x64), K-chunk = 2 slices,
// 3-deep LDS ring (3 x 16 KiB = 48 KiB -> 3 blocks/CU), counted vmcnt(4).

#define NROWS 8192

typedef int   v4i  __attribute__((ext_vector_type(4)));
typedef int   v8i  __attribute__((ext_vector_type(8)));
typedef float v16f __attribute__((ext_vector_type(16)));

#define AS1(p) ((const __attribute__((address_space(1))) void*)(p))
#define AS3(p) ((__attribute__((address_space(3))) void*)(p))

// ---------------- pack (unchanged from R6; proven) --------------------------
__global__ __launch_bounds__(512) void pack_kernel(
    const int* __restrict__ xq, const int* __restrict__ xp,
    uint8_t* __restrict__ qpk, uint8_t* __restrict__ ppk) {
  __shared__ uint8_t lt[64 * 384];      // [rl(64)][c(3)][chunk(8)^swz][16B]
  const int bid = blockIdx.x;           // 512 = 128 R64 * 2 dh * 2 op
  const int op  = bid & 1;
  const int dh  = (bid >> 1) & 1;
  const int R64 = bid >> 2;
  const int t   = threadIdx.x;
  const int* src = op ? xp : xq;
  uint8_t*   dst = op ? ppk : qpk;
  const int row0 = R64 * 64;
  const int d0   = dh * 256;

  #pragma unroll
  for (int i = 0; i < 8; ++i) {
    const int idx = i * 512 + t;
    const int rl = idx >> 6, q = idx & 63;
    const int4 a = ((const int4*)(src + (size_t)(row0 + rl) * 512 + d0))[q];
    const int tok[4] = {a.x, a.y, a.z, a.w};
    uint32_t n0 = 0, n1 = 0, n2 = 0;
    #pragma unroll
    for (int j = 0; j < 4; ++j) {
      const uint32_t b1 = (tok[j] >> 1) & 1, b0 = tok[j] & 1;
      n0 |= (0x2u | (b1 << 3)) << (4 * j);
      n1 |= (0x2u | (b0 << 3)) << (4 * j);
      n2 |= (0x2u | ((b1 ^ b0) << 3)) << (4 * j);
    }
    uint8_t* p = lt + rl * 384 + (((q >> 3) ^ (rl & 7)) << 4) + (q & 7) * 2;
    *(uint16_t*)(p)       = (uint16_t)n0;
    *(uint16_t*)(p + 128) = (uint16_t)n1;
    *(uint16_t*)(p + 256) = (uint16_t)n2;
  }
  __syncthreads();

  const size_t Rg = R64 >> 2;
  const int rb = (R64 & 3) * 64;
  #pragma unroll
  for (int i = 0; i < 3; ++i) {
    const int o = i * 512 + t;
    const int c = o >> 9, sg = (o >> 6) & 7, rl = o & 63;
    const int kt = c * 2 + dh;
    const uint4 v = *(const uint4*)(lt + rl * 384 + c * 128 + ((sg ^ (rl & 7)) << 4));
    *(uint4*)(dst + (((Rg * 6 + kt) * 8 + sg) * 256 + rb + rl) * 16) = v;
  }
}

// ---------------- main GEMM -------------------------------------------------
__global__ __launch_bounds__(256, 3) void hamming_mfma(
    const uint8_t* __restrict__ Apk, const uint8_t* __restrict__ Bpk,
    int* __restrict__ out) {
  // ring chunk = [op(2)][pp(2)][g(2)][j(128)][16B] = 16 KiB; 3 chunks = 48 KiB
  __shared__ __align__(128) uint8_t lds[49152];

  const int t = threadIdx.x, l = t & 63, w = t >> 6;
  const int wr = w >> 1, wc = w & 1;           // wave -> 64x64 sub-tile
  const int g = l >> 5, ll = l & 31;

  // XCD swizzle (4096 % 8 == 0) + 8x8 patches: per-patch ops = 1.5 MB, L2-fit
  const int bid = blockIdx.x;
  const int nid = (bid & 7) * 512 + (bid >> 3);
  const int pch = nid >> 6, q = nid & 63;
  const int br = (pch >> 3) * 8 + (q >> 3);    // 0..63
  const int bc = (pch & 7) * 8 + (q & 7);      // 0..63

  // staging source: instr (op, pp) at chunk c reads
  //   base_op + (2c+pp)*8192 + g2*4096 + (rb_op + j)*16,  g2 = t>>7, j = t&127
  const int g2 = t >> 7, j = t & 127;
  const uint8_t* srcA = Apk + (size_t)(br >> 1) * 196608 + g2 * 4096
                      + ((br & 1) * 128 + j) * 16;
  const uint8_t* srcB = Bpk + (size_t)(bc >> 1) * 196608 + g2 * 4096
                      + ((bc & 1) * 128 + j) * 16;

  #define STAGE(c, buf) do {                                                   \
    __builtin_amdgcn_global_load_lds(AS1(srcA + (2*(c))   * 8192),             \
        AS3(lds + (buf) * 16384 +  0   + t * 16), 16, 0, 0);                   \
    __builtin_amdgcn_global_load_lds(AS1(srcA + (2*(c)+1) * 8192),             \
        AS3(lds + (buf) * 16384 + 4096 + t * 16), 16, 0, 0);                   \
    __builtin_amdgcn_global_load_lds(AS1(srcB + (2*(c))   * 8192),             \
        AS3(lds + (buf) * 16384 + 8192 + t * 16), 16, 0, 0);                   \
    __builtin_amdgcn_global_load_lds(AS1(srcB + (2*(c)+1) * 8192),             \
        AS3(lds + (buf) * 16384 + 12288 + t * 16), 16, 0, 0);                  \
  } while (0)

  v16f acc[2][2] = {};

  STAGE(0, 0);
  STAGE(1, 1);

  const int aoff = g * 2048 + (wr * 64 + ll) * 16;   // + m*512, + pp*4096
  const int boff = 8192 + g * 2048 + (wc * 64 + ll) * 16;

  #pragma unroll
  for (int c = 0; c < 12; ++c) {
    const int buf = c % 3;
    if (c == 11) asm volatile("s_waitcnt vmcnt(0)" ::: "memory");
    else         asm volatile("s_waitcnt vmcnt(4)" ::: "memory");
    __builtin_amdgcn_s_barrier();
    if (c < 10) STAGE(c + 2, (c + 2) % 3);

    const uint8_t* La = lds + buf * 16384;
    v4i af[2][2], bf[2][2];
    #pragma unroll
    for (int pp = 0; pp < 2; ++pp) {
      #pragma unroll
      for (int m = 0; m < 2; ++m)
        af[pp][m] = *(const v4i*)(La + pp * 4096 + aoff + m * 512);
      #pragma unroll
      for (int n = 0; n < 2; ++n)
        bf[pp][n] = *(const v4i*)(La + pp * 4096 + boff + n * 512);
    }
    asm volatile("s_waitcnt lgkmcnt(0)" ::: "memory");
    __builtin_amdgcn_sched_barrier(0);
    __builtin_amdgcn_s_setprio(1);
    #pragma unroll
    for (int pp = 0; pp < 2; ++pp)
      #pragma unroll
      for (int m = 0; m < 2; ++m)
        #pragma unroll
        for (int n = 0; n < 2; ++n) {
          const v8i av = (v8i){af[pp][m][0], af[pp][m][1], af[pp][m][2],
                               af[pp][m][3], 0, 0, 0, 0};
          const v8i bv = (v8i){bf[pp][n][0], bf[pp][n][1], bf[pp][n][2],
                               bf[pp][n][3], 0, 0, 0, 0};
          acc[m][n] = __builtin_amdgcn_mfma_scale_f32_32x32x64_f8f6f4(
              av, bv, acc[m][n], 4 /*fp4 A*/, 4 /*fp4 B*/,
              0, 0x7F7F7F7F, 0, 0x7F7F7F7F);
        }
    __builtin_amdgcn_s_setprio(0);
    __builtin_amdgcn_s_barrier();
  }

  // epilogue: C/D (32x32): col = l&31, row = (reg&3) + 8*(reg>>2) + 4*(l>>5)
  const int rbase = br * 128 + wr * 64 + 4 * g;
  const int cbase = bc * 128 + wc * 64 + ll;
  #pragma unroll
  for (int m = 0; m < 2; ++m)
    #pragma unroll
    for (int n = 0; n < 2; ++n) {
      const int col = cbase + n * 32;
      #pragma unroll
      for (int reg = 0; reg < 16; ++reg) {
        const int orow = rbase + m * 32 + (reg & 3) + 8 * (reg >> 2);
        out[(size_t)orow * NROWS + col] = 512 - (((int)acc[m][n][reg] + 512) >> 2);
      }
    }
}

extern "C" void kernel_launch(void* const* d_in, const int* in_sizes, int n_in,
                              void* d_out, int out_size, void* d_ws, size_t ws_size,
                              hipStream_t stream) {
  const int* xq = (const int*)d_in[0];
  const int* xp = (const int*)d_in[1];
  int* out = (int*)d_out;

  uint8_t* qpk = (uint8_t*)d_ws;                       // 6 MB
  uint8_t* ppk = qpk + (size_t)NROWS * 768;            // 6 MB

  pack_kernel<<<512, 512, 0, stream>>>(xq, xp, qpk, ppk);
  hamming_mfma<<<4096, 256, 0, stream>>>(qpk, ppk, out);
}

// Round 9
// 310.264 us; speedup vs baseline: 1.1025x; 1.0028x over previous
//
#include <hip/hip_runtime.h>
#include <stdint.h>

// Hamming distance as an MX-FP4 MFMA GEMM.
// Token t -> 3 features (s1, s0, s1*s0), s=+-1, fp4 e2m1 (+1=0x2, -1=0xA),
// scales 1.0 (0x7F). dot = 4*matches - 512 => dist = 512 - ((dot+512)>>2).
//
// Packed layout (validated R6): pk[R(32 groups of 256 rows)][s_glob(24)][g(2)][r(256)][16B]
//   = group*196608 + s_glob*8192 + g*4096 + r*16, s_glob = K-chunk of 64 fp4.
//
// R9 = R8 + undef-high MFMA operands (fp4 reads only v[0:3]; shufflevector
// with -1 high lanes kills the 8x v_mov per fragment build).

#define NROWS 8192

typedef int   v4i  __attribute__((ext_vector_type(4)));
typedef int   v8i  __attribute__((ext_vector_type(8)));
typedef float v16f __attribute__((ext_vector_type(16)));

#define AS1(p) ((const __attribute__((address_space(1))) void*)(p))
#define AS3(p) ((__attribute__((address_space(3))) void*)(p))
#define PAD8(v) __builtin_shufflevector((v), (v), 0, 1, 2, 3, -1, -1, -1, -1)

// ---------------- pack (unchanged from R6; proven) --------------------------
__global__ __launch_bounds__(512) void pack_kernel(
    const int* __restrict__ xq, const int* __restrict__ xp,
    uint8_t* __restrict__ qpk, uint8_t* __restrict__ ppk) {
  __shared__ uint8_t lt[64 * 384];      // [rl(64)][c(3)][chunk(8)^swz][16B]
  const int bid = blockIdx.x;           // 512 = 128 R64 * 2 dh * 2 op
  const int op  = bid & 1;
  const int dh  = (bid >> 1) & 1;
  const int R64 = bid >> 2;
  const int t   = threadIdx.x;
  const int* src = op ? xp : xq;
  uint8_t*   dst = op ? ppk : qpk;
  const int row0 = R64 * 64;
  const int d0   = dh * 256;

  #pragma unroll
  for (int i = 0; i < 8; ++i) {
    const int idx = i * 512 + t;
    const int rl = idx >> 6, q = idx & 63;
    const int4 a = ((const int4*)(src + (size_t)(row0 + rl) * 512 + d0))[q];
    const int tok[4] = {a.x, a.y, a.z, a.w};
    uint32_t n0 = 0, n1 = 0, n2 = 0;
    #pragma unroll
    for (int j = 0; j < 4; ++j) {
      const uint32_t b1 = (tok[j] >> 1) & 1, b0 = tok[j] & 1;
      n0 |= (0x2u | (b1 << 3)) << (4 * j);
      n1 |= (0x2u | (b0 << 3)) << (4 * j);
      n2 |= (0x2u | ((b1 ^ b0) << 3)) << (4 * j);
    }
    uint8_t* p = lt + rl * 384 + (((q >> 3) ^ (rl & 7)) << 4) + (q & 7) * 2;
    *(uint16_t*)(p)       = (uint16_t)n0;
    *(uint16_t*)(p + 128) = (uint16_t)n1;
    *(uint16_t*)(p + 256) = (uint16_t)n2;
  }
  __syncthreads();

  const size_t Rg = R64 >> 2;
  const int rb = (R64 & 3) * 64;
  #pragma unroll
  for (int i = 0; i < 3; ++i) {
    const int o = i * 512 + t;
    const int c = o >> 9, sg = (o >> 6) & 7, rl = o & 63;
    const int kt = c * 2 + dh;
    const uint4 v = *(const uint4*)(lt + rl * 384 + c * 128 + ((sg ^ (rl & 7)) << 4));
    *(uint4*)(dst + (((Rg * 6 + kt) * 8 + sg) * 256 + rb + rl) * 16) = v;
  }
}

// ---------------- main GEMM -------------------------------------------------
__global__ __launch_bounds__(256, 3) void hamming_mfma(
    const uint8_t* __restrict__ Apk, const uint8_t* __restrict__ Bpk,
    int* __restrict__ out) {
  // ring chunk = [op(2)][pp(2)][g(2)][j(128)][16B] = 16 KiB; 3 chunks = 48 KiB
  __shared__ __align__(128) uint8_t lds[49152];

  const int t = threadIdx.x, l = t & 63, w = t >> 6;
  const int wr = w >> 1, wc = w & 1;           // wave -> 64x64 sub-tile
  const int g = l >> 5, ll = l & 31;

  // XCD swizzle (4096 % 8 == 0) + 8x8 patches: per-patch ops = 1.5 MB, L2-fit
  const int bid = blockIdx.x;
  const int nid = (bid & 7) * 512 + (bid >> 3);
  const int pch = nid >> 6, q = nid & 63;
  const int br = (pch >> 3) * 8 + (q >> 3);    // 0..63
  const int bc = (pch & 7) * 8 + (q & 7);      // 0..63

  // staging source: instr (op, pp) at chunk c reads
  //   base_op + (2c+pp)*8192 + g2*4096 + (rb_op + j)*16,  g2 = t>>7, j = t&127
  const int g2 = t >> 7, j = t & 127;
  const uint8_t* srcA = Apk + (size_t)(br >> 1) * 196608 + g2 * 4096
                      + ((br & 1) * 128 + j) * 16;
  const uint8_t* srcB = Bpk + (size_t)(bc >> 1) * 196608 + g2 * 4096
                      + ((bc & 1) * 128 + j) * 16;

  #define STAGE(c, buf) do {                                                   \
    __builtin_amdgcn_global_load_lds(AS1(srcA + (2*(c))   * 8192),             \
        AS3(lds + (buf) * 16384 +  0   + t * 16), 16, 0, 0);                   \
    __builtin_amdgcn_global_load_lds(AS1(srcA + (2*(c)+1) * 8192),             \
        AS3(lds + (buf) * 16384 + 4096 + t * 16), 16, 0, 0);                   \
    __builtin_amdgcn_global_load_lds(AS1(srcB + (2*(c))   * 8192),             \
        AS3(lds + (buf) * 16384 + 8192 + t * 16), 16, 0, 0);                   \
    __builtin_amdgcn_global_load_lds(AS1(srcB + (2*(c)+1) * 8192),             \
        AS3(lds + (buf) * 16384 + 12288 + t * 16), 16, 0, 0);                  \
  } while (0)

  v16f acc[2][2] = {};

  STAGE(0, 0);
  STAGE(1, 1);

  const int aoff = g * 2048 + (wr * 64 + ll) * 16;   // + m*512, + pp*4096
  const int boff = 8192 + g * 2048 + (wc * 64 + ll) * 16;

  #pragma unroll
  for (int c = 0; c < 12; ++c) {
    const int buf = c % 3;
    if (c == 11) asm volatile("s_waitcnt vmcnt(0)" ::: "memory");
    else         asm volatile("s_waitcnt vmcnt(4)" ::: "memory");
    __builtin_amdgcn_s_barrier();
    if (c < 10) STAGE(c + 2, (c + 2) % 3);

    const uint8_t* La = lds + buf * 16384;
    v4i af[2][2], bf[2][2];
    #pragma unroll
    for (int pp = 0; pp < 2; ++pp) {
      #pragma unroll
      for (int m = 0; m < 2; ++m)
        af[pp][m] = *(const v4i*)(La + pp * 4096 + aoff + m * 512);
      #pragma unroll
      for (int n = 0; n < 2; ++n)
        bf[pp][n] = *(const v4i*)(La + pp * 4096 + boff + n * 512);
    }
    asm volatile("s_waitcnt lgkmcnt(0)" ::: "memory");
    __builtin_amdgcn_sched_barrier(0);
    __builtin_amdgcn_s_setprio(1);
    #pragma unroll
    for (int pp = 0; pp < 2; ++pp)
      #pragma unroll
      for (int m = 0; m < 2; ++m)
        #pragma unroll
        for (int n = 0; n < 2; ++n) {
          acc[m][n] = __builtin_amdgcn_mfma_scale_f32_32x32x64_f8f6f4(
              PAD8(af[pp][m]), PAD8(bf[pp][n]), acc[m][n],
              4 /*fp4 A*/, 4 /*fp4 B*/, 0, 0x7F7F7F7F, 0, 0x7F7F7F7F);
        }
    __builtin_amdgcn_s_setprio(0);
    __builtin_amdgcn_s_barrier();
  }

  // epilogue: C/D (32x32): col = l&31, row = (reg&3) + 8*(reg>>2) + 4*(l>>5)
  const int rbase = br * 128 + wr * 64 + 4 * g;
  const int cbase = bc * 128 + wc * 64 + ll;
  #pragma unroll
  for (int m = 0; m < 2; ++m)
    #pragma unroll
    for (int n = 0; n < 2; ++n) {
      const int col = cbase + n * 32;
      #pragma unroll
      for (int reg = 0; reg < 16; ++reg) {
        const int orow = rbase + m * 32 + (reg & 3) + 8 * (reg >> 2);
        out[(size_t)orow * NROWS + col] = 512 - (((int)acc[m][n][reg] + 512) >> 2);
      }
    }
}

extern "C" void kernel_launch(void* const* d_in, const int* in_sizes, int n_in,
                              void* d_out, int out_size, void* d_ws, size_t ws_size,
                              hipStream_t stream) {
  const int* xq = (const int*)d_in[0];
  const int* xp = (const int*)d_in[1];
  int* out = (int*)d_out;

  uint8_t* qpk = (uint8_t*)d_ws;                       // 6 MB
  uint8_t* ppk = qpk + (size_t)NROWS * 768;            // 6 MB

  pack_kernel<<<512, 512, 0, stream>>>(xq, xp, qpk, ppk);
  hamming_mfma<<<4096, 256, 0, stream>>>(qpk, ppk, out);
}